// Round 3
// baseline (529.885 us; speedup 1.0000x reference)
//
#include <hip/hip_runtime.h>
#include <hip/hip_bf16.h>

#define N_NODES 4096
#define DIM 256
#define NHEAD 4
#define NEDGE 131072
#define MWORDS 128           // 4096 bits / 32 per mask row
#define MAXDEG 192           // mean deg ~65, sigma ~8; 192 is >15 sigma

#define BM 64
#define BN 64
#define BK 16

// ---------------------------------------------------------------- mask build
__global__ __launch_bounds__(256) void build_mask_kernel(const int* __restrict__ ei,
                                                         unsigned* __restrict__ mask) {
    const int t = blockIdx.x * blockDim.x + threadIdx.x;
    if (t < NEDGE) {
        const int r = ei[t] & (N_NODES - 1);
        const int c = ei[NEDGE + t] & (N_NODES - 1);
        atomicOr(&mask[r * MWORDS + (c >> 5)], 1u << (c & 31));
        atomicOr(&mask[c * MWORDS + (r >> 5)], 1u << (r & 31));
    } else if (t < NEDGE + N_NODES) {
        const int i = t - NEDGE;
        atomicOr(&mask[i * MWORDS + (i >> 5)], 1u << (i & 31));
    }
}

// ---------------------------------------------------------------- fp32 NT GEMM tile
// C[m][n] = sum_k A[m*lda+k] * B[n*ldb+k] + bias[n]
__device__ __forceinline__ void gemm_nt_64x64(const float* __restrict__ A, int lda,
                                              const float* __restrict__ B, int ldb,
                                              const float* __restrict__ bias,
                                              float* __restrict__ C, int ldc,
                                              int bm, int bn, int K) {
    __shared__ float As[BK][BM + 4];
    __shared__ float Bs[BK][BN + 4];
    const int tid = threadIdx.x;
    const int tx = tid & 15;
    const int ty = tid >> 4;
    const int lr = tid >> 2;         // 0..63 : row within tile for loads
    const int lc = (tid & 3) << 2;   // 0,4,8,12 : k-col within chunk
    float acc[4][4] = {{0.f, 0.f, 0.f, 0.f}, {0.f, 0.f, 0.f, 0.f},
                       {0.f, 0.f, 0.f, 0.f}, {0.f, 0.f, 0.f, 0.f}};
    const float* Aload = A + (bm + lr) * lda + lc;
    const float* Bload = B + (bn + lr) * ldb + lc;
    for (int k0 = 0; k0 < K; k0 += BK) {
        const float4 a4 = *(const float4*)(Aload + k0);
        const float4 b4 = *(const float4*)(Bload + k0);
        __syncthreads();
        As[lc + 0][lr] = a4.x; As[lc + 1][lr] = a4.y;
        As[lc + 2][lr] = a4.z; As[lc + 3][lr] = a4.w;
        Bs[lc + 0][lr] = b4.x; Bs[lc + 1][lr] = b4.y;
        Bs[lc + 2][lr] = b4.z; Bs[lc + 3][lr] = b4.w;
        __syncthreads();
#pragma unroll
        for (int k = 0; k < BK; ++k) {
            const float4 av = *(const float4*)&As[k][ty << 2];
            const float4 bv = *(const float4*)&Bs[k][tx << 2];
            acc[0][0] += av.x * bv.x; acc[0][1] += av.x * bv.y;
            acc[0][2] += av.x * bv.z; acc[0][3] += av.x * bv.w;
            acc[1][0] += av.y * bv.x; acc[1][1] += av.y * bv.y;
            acc[1][2] += av.y * bv.z; acc[1][3] += av.y * bv.w;
            acc[2][0] += av.z * bv.x; acc[2][1] += av.z * bv.y;
            acc[2][2] += av.z * bv.z; acc[2][3] += av.z * bv.w;
            acc[3][0] += av.w * bv.x; acc[3][1] += av.w * bv.y;
            acc[3][2] += av.w * bv.z; acc[3][3] += av.w * bv.w;
        }
    }
    const int col = bn + (tx << 2);
    const float4 bia = *(const float4*)&bias[col];
#pragma unroll
    for (int i = 0; i < 4; ++i) {
        const int row = bm + (ty << 2) + i;
        float4 r;
        r.x = acc[i][0] + bia.x;
        r.y = acc[i][1] + bia.y;
        r.z = acc[i][2] + bia.z;
        r.w = acc[i][3] + bia.w;
        *(float4*)&C[row * ldc + col] = r;
    }
}

// q/k/v projections: z = op*4 + head ; out[h][n][e] = x @ W[h]^T + b[h]
__global__ __launch_bounds__(256) void qkv_kernel(const float* __restrict__ x,
                                                  const float* __restrict__ Wq, const float* __restrict__ bq,
                                                  const float* __restrict__ Wk, const float* __restrict__ bk,
                                                  const float* __restrict__ Wv, const float* __restrict__ bv,
                                                  float* __restrict__ q, float* __restrict__ k,
                                                  float* __restrict__ v) {
    const int z = blockIdx.z;
    const int op = z >> 2;
    const int h = z & 3;
    const float* W;
    const float* b;
    float* out;
    if (op == 0)      { W = Wq; b = bq; out = q; }
    else if (op == 1) { W = Wk; b = bk; out = k; }
    else              { W = Wv; b = bv; out = v; }
    gemm_nt_64x64(x, DIM, W + h * DIM * DIM, DIM, b + h * DIM,
                  out + h * N_NODES * DIM, DIM,
                  blockIdx.x * BM, blockIdx.y * BN, DIM);
}

// per-head out-proj, written straight into concat layout [N, H*D]
__global__ __launch_bounds__(256) void headout_kernel(const float* __restrict__ o,
                                                      const float* __restrict__ Wo,
                                                      const float* __restrict__ bo,
                                                      float* __restrict__ concat) {
    const int h = blockIdx.z;
    gemm_nt_64x64(o + h * N_NODES * DIM, DIM, Wo + h * DIM * DIM, DIM, bo + h * DIM,
                  concat + h * DIM, NHEAD * DIM,
                  blockIdx.x * BM, blockIdx.y * BN, DIM);
}

// out = concat [N,1024] @ Wp^T + bp -> [N,256]
__global__ __launch_bounds__(256) void finalproj_kernel(const float* __restrict__ concat,
                                                        const float* __restrict__ Wp,
                                                        const float* __restrict__ bp,
                                                        float* __restrict__ outp) {
    gemm_nt_64x64(concat, NHEAD * DIM, Wp, NHEAD * DIM, bp,
                  outp, DIM,
                  blockIdx.x * BM, blockIdx.y * BN, NHEAD * DIM);
}

// ---------------------------------------------------------------- sparse attention
// one block per node; wave w = head w.
// Phase 0: all threads decode mask row -> LDS neighbor list (shared by 4 heads).
// Phase A: 4 neighbors per wave via 16-lane subgroups -> weights to LDS.
// Phase B: streaming weighted V accumulation (coalesced, no cross-lane ops).
__global__ __launch_bounds__(256) void attn_sparse_kernel(const unsigned* __restrict__ mask,
                                                          const float* __restrict__ q,
                                                          const float* __restrict__ k,
                                                          const float* __restrict__ v,
                                                          float* __restrict__ o) {
    __shared__ int nbr[MAXDEG];
    __shared__ float wts[NHEAD][MAXDEG];
    __shared__ int cnt;
    const int i = blockIdx.x;
    const int tid = threadIdx.x;
    if (tid == 0) cnt = 0;
    __syncthreads();
    // decode: thread t handles mask word t (t < 128)
    if (tid < MWORDS) {
        unsigned m = mask[i * MWORDS + tid];
        while (m) {
            const int b = __ffs(m) - 1;
            m &= m - 1;
            const int pos = atomicAdd(&cnt, 1);
            nbr[pos] = (tid << 5) + b;
        }
    }
    __syncthreads();
    const int deg = cnt;

    const int lane = tid & 63;
    const int h = tid >> 6;
    const int sub = lane >> 4;       // which of 4 concurrent neighbors
    const int sl = lane & 15;        // 16 lanes split the 256-dim dot

    // q fragment: dims {64*c + 4*sl .. +3}, c = 0..3 (independent of sub)
    const float* qrow = q + (((size_t)h * N_NODES + i) << 8);
    float4 qf0 = *(const float4*)(qrow + (sl << 2));
    float4 qf1 = *(const float4*)(qrow + 64 + (sl << 2));
    float4 qf2 = *(const float4*)(qrow + 128 + (sl << 2));
    float4 qf3 = *(const float4*)(qrow + 192 + (sl << 2));

    // ---- Phase A: scores
    const float SC = 0.0625f * 1.44269504f;   // 1/sqrt(256) * log2(e)
    float denom = 0.f;
    for (int n0 = 0; n0 < deg; n0 += 4) {
        const int idx = n0 + sub;
        const bool valid = idx < deg;
        const int j = nbr[valid ? idx : 0];
        const float* kr = k + (((size_t)h * N_NODES + j) << 8);
        const float4 k0 = *(const float4*)(kr + (sl << 2));
        const float4 k1 = *(const float4*)(kr + 64 + (sl << 2));
        const float4 k2 = *(const float4*)(kr + 128 + (sl << 2));
        const float4 k3 = *(const float4*)(kr + 192 + (sl << 2));
        float p = qf0.x * k0.x + qf0.y * k0.y + qf0.z * k0.z + qf0.w * k0.w;
        p += qf1.x * k1.x + qf1.y * k1.y + qf1.z * k1.z + qf1.w * k1.w;
        p += qf2.x * k2.x + qf2.y * k2.y + qf2.z * k2.z + qf2.w * k2.w;
        p += qf3.x * k3.x + qf3.y * k3.y + qf3.z * k3.z + qf3.w * k3.w;
        // reduce across the 16 lanes of this subgroup
        p += __shfl_xor(p, 1);
        p += __shfl_xor(p, 2);
        p += __shfl_xor(p, 4);
        p += __shfl_xor(p, 8);
        const float wt = valid ? __builtin_amdgcn_exp2f(p * SC) : 0.f;
        denom += wt;
        if (valid && sl == 0) wts[h][idx] = wt;
    }
    // denom: every lane in a subgroup holds the same partial; combine across subs
    denom += __shfl_xor(denom, 16);
    denom += __shfl_xor(denom, 32);
    const float inv = 1.0f / denom;

    // no __syncthreads needed: wave h wrote wts[h] and is its only reader

    // ---- Phase B: o_i = sum_j w_j * v_j  (coalesced stream)
    const int dof = lane << 2;
    float4 oa = {0.f, 0.f, 0.f, 0.f};
    int n = 0;
    for (; n + 4 <= deg; n += 4) {
        const float w0 = wts[h][n + 0];
        const float w1 = wts[h][n + 1];
        const float w2 = wts[h][n + 2];
        const float w3 = wts[h][n + 3];
        const float4 v0 = *(const float4*)&v[(((size_t)h * N_NODES + nbr[n + 0]) << 8) + dof];
        const float4 v1 = *(const float4*)&v[(((size_t)h * N_NODES + nbr[n + 1]) << 8) + dof];
        const float4 v2 = *(const float4*)&v[(((size_t)h * N_NODES + nbr[n + 2]) << 8) + dof];
        const float4 v3 = *(const float4*)&v[(((size_t)h * N_NODES + nbr[n + 3]) << 8) + dof];
        oa.x += w0 * v0.x; oa.y += w0 * v0.y; oa.z += w0 * v0.z; oa.w += w0 * v0.w;
        oa.x += w1 * v1.x; oa.y += w1 * v1.y; oa.z += w1 * v1.z; oa.w += w1 * v1.w;
        oa.x += w2 * v2.x; oa.y += w2 * v2.y; oa.z += w2 * v2.z; oa.w += w2 * v2.w;
        oa.x += w3 * v3.x; oa.y += w3 * v3.y; oa.z += w3 * v3.z; oa.w += w3 * v3.w;
    }
    for (; n < deg; ++n) {
        const float w = wts[h][n];
        const float4 vv = *(const float4*)&v[(((size_t)h * N_NODES + nbr[n]) << 8) + dof];
        oa.x += w * vv.x; oa.y += w * vv.y; oa.z += w * vv.z; oa.w += w * vv.w;
    }
    float4 r;
    r.x = oa.x * inv; r.y = oa.y * inv; r.z = oa.z * inv; r.w = oa.w * inv;
    *(float4*)&o[(((size_t)h * N_NODES + i) << 8) + dof] = r;
}

// ---------------------------------------------------------------- layernorm
__global__ __launch_bounds__(256) void layernorm_kernel(const float* __restrict__ inp,
                                                        const float* __restrict__ gamma,
                                                        const float* __restrict__ beta,
                                                        float* __restrict__ out) {
    const int row = (blockIdx.x << 2) + (threadIdx.x >> 6);
    const int lane = threadIdx.x & 63;
    const float4 xv = *(const float4*)&inp[row * DIM + (lane << 2)];
    float s = xv.x + xv.y + xv.z + xv.w;
#pragma unroll
    for (int off = 32; off; off >>= 1) s += __shfl_xor(s, off);
    const float mu = s * (1.0f / DIM);
    const float dx = xv.x - mu, dy = xv.y - mu, dz = xv.z - mu, dw = xv.w - mu;
    float sq = dx * dx + dy * dy + dz * dz + dw * dw;
#pragma unroll
    for (int off = 32; off; off >>= 1) sq += __shfl_xor(sq, off);
    const float inv = 1.0f / sqrtf(sq * (1.0f / DIM) + 1e-5f);
    const float4 gv = *(const float4*)&gamma[lane << 2];
    const float4 bv = *(const float4*)&beta[lane << 2];
    float4 r;
    r.x = dx * inv * gv.x + bv.x;
    r.y = dy * inv * gv.y + bv.y;
    r.z = dz * inv * gv.z + bv.z;
    r.w = dw * inv * gv.w + bv.w;
    *(float4*)&out[row * DIM + (lane << 2)] = r;
}

// ---------------------------------------------------------------- launcher
extern "C" void kernel_launch(void* const* d_in, const int* in_sizes, int n_in,
                              void* d_out, int out_size, void* d_ws, size_t ws_size,
                              hipStream_t stream) {
    const float* x     = (const float*)d_in[0];
    const int*   ei    = (const int*)d_in[1];
    const float* Wq    = (const float*)d_in[2];
    const float* bq    = (const float*)d_in[3];
    const float* Wk    = (const float*)d_in[4];
    const float* bk    = (const float*)d_in[5];
    const float* Wv    = (const float*)d_in[6];
    const float* bv    = (const float*)d_in[7];
    const float* Wo    = (const float*)d_in[8];
    const float* bo    = (const float*)d_in[9];
    const float* Wp    = (const float*)d_in[10];
    const float* bp    = (const float*)d_in[11];
    const float* gamma = (const float*)d_in[12];
    const float* beta  = (const float*)d_in[13];
    float* outf = (float*)d_out;

    char* ws = (char*)d_ws;
    unsigned* mask = (unsigned*)ws;                       // 2 MB
    float* q = (float*)(ws + (size_t)(2 << 20));          // 16 MB each
    float* k = q + (size_t)NHEAD * N_NODES * DIM;
    float* v = k + (size_t)NHEAD * N_NODES * DIM;
    float* o = v + (size_t)NHEAD * N_NODES * DIM;
    float* concat = q;                                    // alias (q dead after attn)
    float* outp   = k;                                    // alias (k dead after attn)

    hipMemsetAsync(mask, 0, N_NODES * MWORDS * sizeof(unsigned), stream);
    build_mask_kernel<<<(NEDGE + N_NODES + 255) / 256, 256, 0, stream>>>(ei, mask);

    qkv_kernel<<<dim3(N_NODES / BM, DIM / BN, 12), 256, 0, stream>>>(
        x, Wq, bq, Wk, bk, Wv, bv, q, k, v);

    attn_sparse_kernel<<<N_NODES, 256, 0, stream>>>(mask, q, k, v, o);

    headout_kernel<<<dim3(N_NODES / BM, DIM / BN, NHEAD), 256, 0, stream>>>(o, Wo, bo, concat);

    finalproj_kernel<<<dim3(N_NODES / BM, DIM / BN), 256, 0, stream>>>(concat, Wp, bp, outp);

    layernorm_kernel<<<N_NODES / 4, 256, 0, stream>>>(outp, gamma, beta, outf);
}